// Round 1
// baseline (297.360 us; speedup 1.0000x reference)
//
#include <hip/hip_runtime.h>
#include <hip/hip_bf16.h>
#include <stdint.h>

#define DM 1024
#define SZ ((size_t)8192*1024)      // elems of one [8192][1024] matrix
#define WSZ ((size_t)1024*1024)     // elems of one [1024][1024] weight

typedef float  f32x4  __attribute__((ext_vector_type(4)));
typedef __bf16 bf16x8 __attribute__((ext_vector_type(8)));
typedef short  s16x8  __attribute__((ext_vector_type(8)));

typedef const __attribute__((address_space(1))) void* gas_ptr;
typedef __attribute__((address_space(3))) void* las_ptr;

static __device__ __forceinline__ f32x4 mfma16(s16x8 a, s16x8 b, f32x4 c){
  return __builtin_amdgcn_mfma_f32_16x16x32_bf16(
      __builtin_bit_cast(bf16x8, a), __builtin_bit_cast(bf16x8, b), c, 0, 0, 0);
}

static __device__ __forceinline__ unsigned short f2bf(float f){
  unsigned int u = __builtin_bit_cast(unsigned int, f);
  u += 0x7FFFu + ((u >> 16) & 1u);
  return (unsigned short)(u >> 16);
}

static __device__ __forceinline__ void gload_lds16(void* l, const void* g){
  __builtin_amdgcn_global_load_lds((gas_ptr)g, (las_ptr)l, 16, 0, 0);
}

// ---------------- conversion kernels ----------------

// queries/keys/values fp32 -> bf16 at ws[0..3SZ); Wout fp32 -> bf16 at ws[6SZ+3WSZ)
__global__ void convert_misc(const float* __restrict__ q, const float* __restrict__ k,
                             const float* __restrict__ v, const float* __restrict__ wo,
                             short* __restrict__ ws){
  const size_t n8_in  = (3*SZ)/8;
  const size_t n8_tot = n8_in + WSZ/8;
  size_t stride = (size_t)gridDim.x * blockDim.x;
  for (size_t c = (size_t)blockIdx.x*blockDim.x + threadIdx.x; c < n8_tot; c += stride){
    const float* src; short* dst;
    if (c < n8_in){
      size_t e = c*8;
      int s = (int)(e / SZ);
      size_t off = e - (size_t)s*SZ;
      src = (s==0 ? q : (s==1 ? k : v)) + off;
      dst = ws + e;
    } else {
      size_t off = (c - n8_in)*8;
      src = wo + off;
      dst = ws + 6*SZ + 3*WSZ + off;
    }
    float4 a = *(const float4*)src;
    float4 b = *(const float4*)(src + 4);
    s16x8 o;
    o[0]=(short)f2bf(a.x); o[1]=(short)f2bf(a.y); o[2]=(short)f2bf(a.z); o[3]=(short)f2bf(a.w);
    o[4]=(short)f2bf(b.x); o[5]=(short)f2bf(b.y); o[6]=(short)f2bf(b.z); o[7]=(short)f2bf(b.w);
    *(s16x8*)dst = o;
  }
}

// Wq/Wk/Wv [16][1024][64] -> Bt[n=h*64+k][d] bf16 at ws[6SZ + sel*WSZ)
__global__ void convert_wqkv(const float* __restrict__ wq, const float* __restrict__ wk,
                             const float* __restrict__ wv, short* __restrict__ ws){
  __shared__ float tile[64][65];
  int bid = blockIdx.x;
  int sel = bid >> 8;          // 0..2
  int h   = (bid >> 4) & 15;
  int dt  = bid & 15;
  const float* W = sel==0 ? wq : (sel==1 ? wk : wv);
  short* Bt = ws + 6*SZ + (size_t)sel*WSZ;
  int tid = threadIdx.x;
  int r = tid >> 4, c4 = (tid & 15)*4;
  int d0 = dt*64;
  #pragma unroll
  for (int i=0;i<4;i++){
    int d = r + i*16;
    float4 vv = *(const float4*)&W[(size_t)h*65536 + (size_t)(d0+d)*64 + c4];
    tile[d][c4+0]=vv.x; tile[d][c4+1]=vv.y; tile[d][c4+2]=vv.z; tile[d][c4+3]=vv.w;
  }
  __syncthreads();
  #pragma unroll
  for (int i=0;i<4;i++){
    int kk = r + i*16;
    unsigned int lo = (unsigned)f2bf(tile[c4+0][kk]) | ((unsigned)f2bf(tile[c4+1][kk])<<16);
    unsigned int hi = (unsigned)f2bf(tile[c4+2][kk]) | ((unsigned)f2bf(tile[c4+3][kk])<<16);
    *(uint2*)&Bt[(size_t)(h*64+kk)*1024 + d0 + c4] = make_uint2(lo, hi);
  }
}

// ---------------- GEMM core (128x128 tile, BK=32, 4 waves) ----------------

static __device__ __forceinline__ void gemm_core(
    const short* __restrict__ A, const short* __restrict__ Bt,
    int bm, int bn, short* As, short* Bs, f32x4 acc[4][4])
{
  int tid = threadIdx.x;
  int w = tid>>6, lane = tid&63;
  int wm = w>>1, wn = w&1;
  int col = lane&15, kg = lane>>4;
  int rs = w*16 + (lane>>2);
  int ch = lane&3;

  auto stage = [&](int buf, int kt){
    #pragma unroll
    for (int it=0; it<2; ++it){
      int r = rs + it*64;
      gload_lds16(As + buf*4096 + r*32 + ch*8,
                  A + (size_t)(bm*128 + r)*1024 + kt*32 + ch*8);
    }
    #pragma unroll
    for (int it=0; it<2; ++it){
      int r = rs + it*64;
      gload_lds16(Bs + buf*4096 + r*32 + ch*8,
                  Bt + (size_t)(bn*128 + r)*1024 + kt*32 + ch*8);
    }
  };

  const f32x4 fzero = {0.f,0.f,0.f,0.f};
  #pragma unroll
  for (int mf=0; mf<4; ++mf)
    #pragma unroll
    for (int nf=0; nf<4; ++nf)
      acc[mf][nf] = fzero;

  stage(0, 0);
  int buf = 0;
  for (int kt=0; kt<32; ++kt){
    __syncthreads();
    if (kt < 31) stage(buf^1, kt+1);
    s16x8 af[4], bfr[4];
    #pragma unroll
    for (int mf=0; mf<4; ++mf)
      af[mf] = *(const s16x8*)(As + buf*4096 + (wm*64 + mf*16 + col)*32 + kg*8);
    #pragma unroll
    for (int nf=0; nf<4; ++nf)
      bfr[nf] = *(const s16x8*)(Bs + buf*4096 + (wn*64 + nf*16 + col)*32 + kg*8);
    #pragma unroll
    for (int mf=0; mf<4; ++mf)
      #pragma unroll
      for (int nf=0; nf<4; ++nf)
        acc[mf][nf] = mfma16(af[mf], bfr[nf], acc[mf][nf]);
    buf ^= 1;
  }
}

// fused QKV projection: grid 1536 = 64 m-blocks x (3 mats x 8 n-blocks)
__global__ __launch_bounds__(256,2) void gemm_qkv(short* __restrict__ ws){
  __shared__ __align__(16) short As[2*4096];
  __shared__ __align__(16) short Bs[2*4096];
  int bid = blockIdx.x;
  bid = (bid & 7)*192 + (bid >> 3);          // XCD swizzle (1536 % 8 == 0)
  int bm = bid / 24, bnq = bid % 24;
  int sel = bnq >> 3, bn = bnq & 7;
  const short* A  = ws + (size_t)sel*SZ;
  const short* Bt = ws + 6*SZ + (size_t)sel*WSZ;
  f32x4 acc[4][4];
  gemm_core(A, Bt, bm, bn, As, Bs, acc);

  int tid = threadIdx.x, w = tid>>6, lane = tid&63;
  int wm=w>>1, wn=w&1, col=lane&15, kg=lane>>4;
  if (sel < 2){
    short* O = ws + (size_t)(3+sel)*SZ;      // qp at 3SZ, kp at 4SZ
    #pragma unroll
    for (int mf=0; mf<4; ++mf){
      int gr0 = bm*128 + wm*64 + mf*16 + kg*4;
      #pragma unroll
      for (int nf=0; nf<4; ++nf){
        int gc = bn*128 + wn*64 + nf*16 + col;
        #pragma unroll
        for (int r=0; r<4; ++r)
          O[(size_t)(gr0+r)*1024 + gc] = (short)f2bf(acc[mf][nf][r]);
      }
    }
  } else {
    short* V = ws + 5*SZ;                    // vT[b][h][dv][s]
    #pragma unroll
    for (int mf=0; mf<4; ++mf){
      int gr0 = bm*128 + wm*64 + mf*16 + kg*4;
      int b = gr0 >> 11, s0 = gr0 & 2047;
      #pragma unroll
      for (int nf=0; nf<4; ++nf){
        int gc = bn*128 + wn*64 + nf*16 + col;
        int h = gc >> 6, dv = gc & 63;
        unsigned int lo = (unsigned)f2bf(acc[mf][nf][0]) | ((unsigned)f2bf(acc[mf][nf][1])<<16);
        unsigned int hi = (unsigned)f2bf(acc[mf][nf][2]) | ((unsigned)f2bf(acc[mf][nf][3])<<16);
        *(uint2*)&V[((size_t)((b*16+h)*64+dv))*2048 + s0] = make_uint2(lo, hi);
      }
    }
  }
}

// output projection: concat[8192][1024] x Wout^T + bias -> fp32
__global__ __launch_bounds__(256,2) void gemm_out(const short* __restrict__ cc,
                                                  const short* __restrict__ BtO,
                                                  const float* __restrict__ bias,
                                                  float* __restrict__ out){
  __shared__ __align__(16) short As[2*4096];
  __shared__ __align__(16) short Bs[2*4096];
  int bid = blockIdx.x;
  bid = (bid & 7)*64 + (bid >> 3);           // XCD swizzle (512 % 8 == 0)
  int bm = bid >> 3, bn = bid & 7;
  f32x4 acc[4][4];
  gemm_core(cc, BtO, bm, bn, As, Bs, acc);

  int tid = threadIdx.x, w=tid>>6, lane=tid&63;
  int wm=w>>1, wn=w&1, col=lane&15, kg=lane>>4;
  #pragma unroll
  for (int nf=0; nf<4; ++nf){
    int gc = bn*128 + wn*64 + nf*16 + col;
    float bb = bias[gc];
    #pragma unroll
    for (int mf=0; mf<4; ++mf){
      int gr0 = bm*128 + wm*64 + mf*16 + kg*4;
      #pragma unroll
      for (int r=0; r<4; ++r)
        out[(size_t)(gr0+r)*1024 + gc] = acc[mf][nf][r] + bb;
    }
  }
}

// ---------------- flash attention ----------------
// 4 waves x 16 q-rows, KVBLK=64, S^T = K*Q^T (swapped), P via per-wave LDS.
#define LOG2E 1.4426950408889634f
__global__ __launch_bounds__(256,3) void attn(const short* __restrict__ qp,
                                              const short* __restrict__ kp,
                                              const short* __restrict__ vT,
                                              short* __restrict__ cc){
  __shared__ __align__(16) short Ks[2][4096];
  __shared__ __align__(16) short Vs[2][4096];
  __shared__ __align__(16) short Pl[4][16*88];
  int bid = blockIdx.x;
  bid = (bid & 7)*256 + (bid >> 3);          // XCD swizzle (2048 % 8 == 0)
  int qt = bid & 31, h = (bid>>5) & 15, b = bid >> 9;
  int tid = threadIdx.x, w = tid>>6, lane = tid&63;
  int col = lane&15, kg = lane>>4;
  int qrow = qt*64 + w*16 + col;

  const short* qg = qp + ((size_t)(b*2048 + qrow))*1024 + h*64;
  s16x8 qf0 = *(const s16x8*)(qg + kg*8);
  s16x8 qf1 = *(const s16x8*)(qg + 32 + kg*8);

  const short* kb = kp + (size_t)(b*2048)*1024 + h*64;
  const short* vb = vT + (size_t)((b*16 + h)*64)*2048;

  f32x4 o[4];
  const f32x4 fzero = {0.f,0.f,0.f,0.f};
  #pragma unroll
  for (int mf=0; mf<4; ++mf) o[mf] = fzero;
  float m = -INFINITY, l = 0.f;

  int rl = lane>>3, chc = lane&7;
  auto stage = [&](int buf, int t0){
    #pragma unroll
    for (int it=0; it<2; ++it){
      int r = (it*4 + w)*8 + rl;
      int cs = chc ^ (r & 7);
      gload_lds16(&Ks[buf][r*64 + chc*8], kb + (size_t)(t0 + r)*1024 + cs*8);
    }
    #pragma unroll
    for (int it=0; it<2; ++it){
      int r = (it*4 + w)*8 + rl;
      int cs = chc ^ (r & 7);
      gload_lds16(&Vs[buf][r*64 + chc*8], vb + (size_t)r*2048 + t0 + cs*8);
    }
  };

  stage(0, 0);
  int buf = 0;
  for (int t = 0; t < 32; ++t){
    __syncthreads();
    if (t < 31) stage(buf^1, (t+1)*64);

    // S^T = K * Q^T   (rows t, cols q)
    f32x4 st[4];
    #pragma unroll
    for (int f=0; f<4; ++f) st[f] = fzero;
    #pragma unroll
    for (int ks=0; ks<2; ++ks){
      s16x8 qk = ks ? qf1 : qf0;
      #pragma unroll
      for (int f=0; f<4; ++f){
        int tr = f*16 + col;
        int cidx = (ks*4 + kg) ^ (tr & 7);
        s16x8 kf = *(const s16x8*)((const char*)Ks[buf] + tr*128 + cidx*16);
        st[f] = mfma16(kf, qk, st[f]);
      }
    }

    // online softmax over t (per q = col)
    float pm = -INFINITY;
    #pragma unroll
    for (int f=0; f<4; ++f)
      #pragma unroll
      for (int r=0; r<4; ++r){
        float s = st[f][r]*0.125f;
        st[f][r] = s;
        pm = fmaxf(pm, s);
      }
    pm = fmaxf(pm, __shfl_xor(pm, 16));
    pm = fmaxf(pm, __shfl_xor(pm, 32));
    float mn = fmaxf(m, pm);
    float corr = exp2f((m - mn)*LOG2E);
    float ps = 0.f;
    #pragma unroll
    for (int f=0; f<4; ++f)
      #pragma unroll
      for (int r=0; r<4; ++r){
        float p = exp2f((st[f][r] - mn)*LOG2E);
        st[f][r] = p;
        ps += p;
      }
    ps += __shfl_xor(ps, 16);
    ps += __shfl_xor(ps, 32);
    l = l*corr + ps;
    m = mn;
    #pragma unroll
    for (int mf=0; mf<4; ++mf) o[mf] *= corr;

    // pack P -> per-wave LDS [q][t], padded to 88
    #pragma unroll
    for (int f=0; f<4; ++f){
      unsigned int lo = (unsigned)f2bf(st[f][0]) | ((unsigned)f2bf(st[f][1])<<16);
      unsigned int hi = (unsigned)f2bf(st[f][2]) | ((unsigned)f2bf(st[f][3])<<16);
      *(uint2*)&Pl[w][col*88 + f*16 + kg*4] = make_uint2(lo, hi);
    }

    // O^T += V^T * P^T   (rows dv, cols q)
    #pragma unroll
    for (int ks=0; ks<2; ++ks){
      s16x8 pf = *(const s16x8*)&Pl[w][col*88 + ks*32 + kg*8];
      #pragma unroll
      for (int mf=0; mf<4; ++mf){
        int dv = mf*16 + col;
        int cidx = (ks*4 + kg) ^ (dv & 7);
        s16x8 vf = *(const s16x8*)((const char*)Vs[buf] + dv*128 + cidx*16);
        o[mf] = mfma16(vf, pf, o[mf]);
      }
    }
    buf ^= 1;
  }

  float rcl = 1.0f / l;
  short* og = cc + ((size_t)(b*2048 + qrow))*1024 + h*64;
  #pragma unroll
  for (int mf=0; mf<4; ++mf){
    unsigned int lo = (unsigned)f2bf(o[mf][0]*rcl) | ((unsigned)f2bf(o[mf][1]*rcl)<<16);
    unsigned int hi = (unsigned)f2bf(o[mf][2]*rcl) | ((unsigned)f2bf(o[mf][3]*rcl)<<16);
    *(uint2*)&og[mf*16 + kg*4] = make_uint2(lo, hi);
  }
}

// ---------------- launch ----------------

extern "C" void kernel_launch(void* const* d_in, const int* in_sizes, int n_in,
                              void* d_out, int out_size, void* d_ws, size_t ws_size,
                              hipStream_t stream){
  const float* q  = (const float*)d_in[0];
  const float* k  = (const float*)d_in[1];
  const float* v  = (const float*)d_in[2];
  const float* wq = (const float*)d_in[3];
  const float* wk = (const float*)d_in[4];
  const float* wv = (const float*)d_in[5];
  const float* wo = (const float*)d_in[6];
  const float* bo = (const float*)d_in[7];
  short* ws = (short*)d_ws;
  float* out = (float*)d_out;

  // ws layout (bf16 elems): [0,3SZ) A_q/A_k/A_v (concat reuses [0,SZ) later)
  // [3SZ) qp, [4SZ) kp, [5SZ) vT, [6SZ) BtQ,BtK,BtV, [6SZ+3WSZ) BtO
  size_t needed = (6*SZ + 4*WSZ)*sizeof(short);
  if (ws_size < needed) return;   // would corrupt memory otherwise; fail cleanly

  convert_misc<<<2048, 256, 0, stream>>>(q, k, v, wo, ws);
  convert_wqkv<<<768, 256, 0, stream>>>(wq, wk, wv, ws);
  gemm_qkv<<<1536, 256, 0, stream>>>(ws);
  attn<<<2048, 256, 0, stream>>>(ws + 3*SZ, ws + 4*SZ, ws + 5*SZ, ws);
  gemm_out<<<512, 256, 0, stream>>>(ws, ws + 6*SZ + 3*WSZ, bo, out);
}

// Round 2
// 253.191 us; speedup vs baseline: 1.1744x; 1.1744x over previous
//
#include <hip/hip_runtime.h>
#include <hip/hip_bf16.h>
#include <stdint.h>

#define DM 1024
#define SZ ((size_t)8192*1024)      // elems of one [8192][1024] matrix
#define WSZ ((size_t)1024*1024)     // elems of one [1024][1024] weight

typedef float  f32x4  __attribute__((ext_vector_type(4)));
typedef __bf16 bf16x8 __attribute__((ext_vector_type(8)));
typedef __bf16 bf16x2 __attribute__((ext_vector_type(2)));
typedef short  s16x8  __attribute__((ext_vector_type(8)));

typedef const __attribute__((address_space(1))) void* gas_ptr;
typedef __attribute__((address_space(3))) void* las_ptr;

static __device__ __forceinline__ f32x4 mfma16(s16x8 a, s16x8 b, f32x4 c){
  return __builtin_amdgcn_mfma_f32_16x16x32_bf16(
      __builtin_bit_cast(bf16x8, a), __builtin_bit_cast(bf16x8, b), c, 0, 0, 0);
}

// packed f32x2 -> bf16x2 (compiler emits v_cvt_pk_bf16_f32, RNE)
static __device__ __forceinline__ unsigned int pack2(float a, float b){
  bf16x2 v = { (__bf16)a, (__bf16)b };
  return __builtin_bit_cast(unsigned int, v);
}
static __device__ __forceinline__ short f2bf(float f){
  __bf16 v = (__bf16)f;
  return __builtin_bit_cast(short, v);
}

static __device__ __forceinline__ void gload_lds16(void* l, const void* g){
  __builtin_amdgcn_global_load_lds((gas_ptr)g, (las_ptr)l, 16, 0, 0);
}

#define QSCALE 0.1803368801111444f   /* 0.125 * log2(e): folded into Wq */

// ---------------- conversion kernels ----------------

__global__ void convert_misc(const float* __restrict__ q, const float* __restrict__ k,
                             const float* __restrict__ v, const float* __restrict__ wo,
                             short* __restrict__ ws){
  const size_t n8_in  = (3*SZ)/8;
  const size_t n8_tot = n8_in + WSZ/8;
  size_t stride = (size_t)gridDim.x * blockDim.x;
  for (size_t c = (size_t)blockIdx.x*blockDim.x + threadIdx.x; c < n8_tot; c += stride){
    const float* src; short* dst;
    if (c < n8_in){
      size_t e = c*8;
      int s = (int)(e / SZ);
      size_t off = e - (size_t)s*SZ;
      src = (s==0 ? q : (s==1 ? k : v)) + off;
      dst = ws + e;
    } else {
      size_t off = (c - n8_in)*8;
      src = wo + off;
      dst = ws + 6*SZ + 3*WSZ + off;
    }
    float4 a = *(const float4*)src;
    float4 b = *(const float4*)(src + 4);
    uint4 o;
    o.x = pack2(a.x, a.y); o.y = pack2(a.z, a.w);
    o.z = pack2(b.x, b.y); o.w = pack2(b.z, b.w);
    *(uint4*)dst = o;
  }
}

// Wq/Wk/Wv [16][1024][64] -> Bt[n=h*64+k][d] bf16; Wq scaled by QSCALE
__global__ void convert_wqkv(const float* __restrict__ wq, const float* __restrict__ wk,
                             const float* __restrict__ wv, short* __restrict__ ws){
  __shared__ float tile[64][65];
  int bid = blockIdx.x;
  int sel = bid >> 8;          // 0..2
  int h   = (bid >> 4) & 15;
  int dt  = bid & 15;
  const float* W = sel==0 ? wq : (sel==1 ? wk : wv);
  float sc = sel==0 ? QSCALE : 1.0f;
  short* Bt = ws + 6*SZ + (size_t)sel*WSZ;
  int tid = threadIdx.x;
  int r = tid >> 4, c4 = (tid & 15)*4;
  int d0 = dt*64;
  #pragma unroll
  for (int i=0;i<4;i++){
    int d = r + i*16;
    float4 vv = *(const float4*)&W[(size_t)h*65536 + (size_t)(d0+d)*64 + c4];
    tile[d][c4+0]=vv.x*sc; tile[d][c4+1]=vv.y*sc; tile[d][c4+2]=vv.z*sc; tile[d][c4+3]=vv.w*sc;
  }
  __syncthreads();
  #pragma unroll
  for (int i=0;i<4;i++){
    int kk = r + i*16;
    unsigned int lo = pack2(tile[c4+0][kk], tile[c4+1][kk]);
    unsigned int hi = pack2(tile[c4+2][kk], tile[c4+3][kk]);
    *(uint2*)&Bt[(size_t)(h*64+kk)*1024 + d0 + c4] = make_uint2(lo, hi);
  }
}

// ---------------- GEMM core (128x128 tile, BK=32, 4 waves) ----------------

static __device__ __forceinline__ void gemm_core(
    const short* __restrict__ A, const short* __restrict__ Bt,
    int bm, int bn, short* As, short* Bs, f32x4 acc[4][4])
{
  int tid = threadIdx.x;
  int w = tid>>6, lane = tid&63;
  int wm = w>>1, wn = w&1;
  int col = lane&15, kg = lane>>4;
  int rs = w*16 + (lane>>2);
  int ch = lane&3;

  auto stage = [&](int buf, int kt){
    #pragma unroll
    for (int it=0; it<2; ++it){
      int r = rs + it*64;
      gload_lds16(As + buf*4096 + r*32 + ch*8,
                  A + (size_t)(bm*128 + r)*1024 + kt*32 + ch*8);
    }
    #pragma unroll
    for (int it=0; it<2; ++it){
      int r = rs + it*64;
      gload_lds16(Bs + buf*4096 + r*32 + ch*8,
                  Bt + (size_t)(bn*128 + r)*1024 + kt*32 + ch*8);
    }
  };

  const f32x4 fzero = {0.f,0.f,0.f,0.f};
  #pragma unroll
  for (int mf=0; mf<4; ++mf)
    #pragma unroll
    for (int nf=0; nf<4; ++nf)
      acc[mf][nf] = fzero;

  stage(0, 0);
  int buf = 0;
  for (int kt=0; kt<32; ++kt){
    __syncthreads();
    if (kt < 31) stage(buf^1, kt+1);
    s16x8 af[4], bfr[4];
    #pragma unroll
    for (int mf=0; mf<4; ++mf)
      af[mf] = *(const s16x8*)(As + buf*4096 + (wm*64 + mf*16 + col)*32 + kg*8);
    #pragma unroll
    for (int nf=0; nf<4; ++nf)
      bfr[nf] = *(const s16x8*)(Bs + buf*4096 + (wn*64 + nf*16 + col)*32 + kg*8);
    #pragma unroll
    for (int mf=0; mf<4; ++mf)
      #pragma unroll
      for (int nf=0; nf<4; ++nf)
        acc[mf][nf] = mfma16(af[mf], bfr[nf], acc[mf][nf]);
    buf ^= 1;
  }
}

// fused QKV projection: grid 1536 = 64 m-blocks x (3 mats x 8 n-blocks)
__global__ __launch_bounds__(256,2) void gemm_qkv(short* __restrict__ ws){
  __shared__ __align__(16) short As[2*4096];
  __shared__ __align__(16) short Bs[2*4096];
  int bid = blockIdx.x;
  bid = (bid & 7)*192 + (bid >> 3);          // XCD swizzle (1536 % 8 == 0)
  int bm = bid / 24, bnq = bid % 24;
  int sel = bnq >> 3, bn = bnq & 7;
  const short* A  = ws + (size_t)sel*SZ;
  const short* Bt = ws + 6*SZ + (size_t)sel*WSZ;
  f32x4 acc[4][4];
  gemm_core(A, Bt, bm, bn, As, Bs, acc);

  int tid = threadIdx.x, w = tid>>6, lane = tid&63;
  int wm=w>>1, wn=w&1, col=lane&15, kg=lane>>4;
  if (sel < 2){
    short* O = ws + (size_t)(3+sel)*SZ;      // qp at 3SZ, kp at 4SZ
    #pragma unroll
    for (int mf=0; mf<4; ++mf){
      int gr0 = bm*128 + wm*64 + mf*16 + kg*4;
      #pragma unroll
      for (int nf=0; nf<4; ++nf){
        int gc = bn*128 + wn*64 + nf*16 + col;
        #pragma unroll
        for (int r=0; r<4; ++r)
          O[(size_t)(gr0+r)*1024 + gc] = f2bf(acc[mf][nf][r]);
      }
    }
  } else {
    short* V = ws + 5*SZ;                    // vT[b][h][dv][s]
    #pragma unroll
    for (int mf=0; mf<4; ++mf){
      int gr0 = bm*128 + wm*64 + mf*16 + kg*4;
      int b = gr0 >> 11, s0 = gr0 & 2047;
      #pragma unroll
      for (int nf=0; nf<4; ++nf){
        int gc = bn*128 + wn*64 + nf*16 + col;
        int h = gc >> 6, dv = gc & 63;
        unsigned int lo = pack2(acc[mf][nf][0], acc[mf][nf][1]);
        unsigned int hi = pack2(acc[mf][nf][2], acc[mf][nf][3]);
        *(uint2*)&V[((size_t)((b*16+h)*64+dv))*2048 + s0] = make_uint2(lo, hi);
      }
    }
  }
}

// output projection: concat[8192][1024] x Wout^T + bias -> fp32
__global__ __launch_bounds__(256,2) void gemm_out(const short* __restrict__ cc,
                                                  const short* __restrict__ BtO,
                                                  const float* __restrict__ bias,
                                                  float* __restrict__ out){
  __shared__ __align__(16) short As[2*4096];
  __shared__ __align__(16) short Bs[2*4096];
  int bid = blockIdx.x;
  bid = (bid & 7)*64 + (bid >> 3);           // XCD swizzle (512 % 8 == 0)
  int bm = bid >> 3, bn = bid & 7;
  f32x4 acc[4][4];
  gemm_core(cc, BtO, bm, bn, As, Bs, acc);

  int tid = threadIdx.x, w=tid>>6, lane=tid&63;
  int wm=w>>1, wn=w&1, col=lane&15, kg=lane>>4;
  #pragma unroll
  for (int nf=0; nf<4; ++nf){
    int gc = bn*128 + wn*64 + nf*16 + col;
    float bb = bias[gc];
    #pragma unroll
    for (int mf=0; mf<4; ++mf){
      int gr0 = bm*128 + wm*64 + mf*16 + kg*4;
      #pragma unroll
      for (int r=0; r<4; ++r)
        out[(size_t)(gr0+r)*1024 + gc] = acc[mf][nf][r] + bb;
    }
  }
}

// ---------------- flash attention ----------------
// 4 waves x 16 q-rows, KVBLK=64, S^T = K*Q^T (swapped).
// Scores arrive pre-scaled by 0.125*log2e (folded into Wq) -> exp2 domain.
// Defer-max (THR=4 in log2 units, P <= 16), per-lane partial l.
// LDS exactly 40KB -> 4 blocks/CU.
__global__ __launch_bounds__(256,4) void attn(const short* __restrict__ qp,
                                              const short* __restrict__ kp,
                                              const short* __restrict__ vT,
                                              short* __restrict__ cc){
  __shared__ __align__(16) short Ks[2][4096];
  __shared__ __align__(16) short Vs[2][4096];
  __shared__ __align__(16) short Pl[4][1024];   // per-wave [16 q][64 t], XOR-swizzled
  int bid = blockIdx.x;
  bid = (bid & 7)*256 + (bid >> 3);          // XCD swizzle (2048 % 8 == 0)
  int qt = bid & 31, h = (bid>>5) & 15, b = bid >> 9;
  int tid = threadIdx.x, w = tid>>6, lane = tid&63;
  int col = lane&15, kg = lane>>4;
  int qrow = qt*64 + w*16 + col;

  const short* qg = qp + ((size_t)(b*2048 + qrow))*1024 + h*64;
  s16x8 qf0 = *(const s16x8*)(qg + kg*8);
  s16x8 qf1 = *(const s16x8*)(qg + 32 + kg*8);

  const short* kb = kp + (size_t)(b*2048)*1024 + h*64;
  const short* vb = vT + (size_t)((b*16 + h)*64)*2048;

  f32x4 o[4];
  const f32x4 fzero = {0.f,0.f,0.f,0.f};
  #pragma unroll
  for (int mf=0; mf<4; ++mf) o[mf] = fzero;
  float m = -1.0e30f, l = 0.f;

  int rl = lane>>3, chc = lane&7;
  auto stage = [&](int buf, int t0){
    #pragma unroll
    for (int it=0; it<2; ++it){
      int r = (it*4 + w)*8 + rl;
      int cs = chc ^ (r & 7);
      gload_lds16(&Ks[buf][r*64 + chc*8], kb + (size_t)(t0 + r)*1024 + cs*8);
    }
    #pragma unroll
    for (int it=0; it<2; ++it){
      int r = (it*4 + w)*8 + rl;
      int cs = chc ^ (r & 7);
      gload_lds16(&Vs[buf][r*64 + chc*8], vb + (size_t)r*2048 + t0 + cs*8);
    }
  };

  stage(0, 0);
  int buf = 0;
  for (int t = 0; t < 32; ++t){
    __syncthreads();
    if (t < 31) stage(buf^1, (t+1)*64);

    // S^T = K * Q^T   (rows t, cols q); already in log2 units
    f32x4 st[4];
    #pragma unroll
    for (int f=0; f<4; ++f) st[f] = fzero;
    #pragma unroll
    for (int ks=0; ks<2; ++ks){
      s16x8 qk = ks ? qf1 : qf0;
      #pragma unroll
      for (int f=0; f<4; ++f){
        int tr = f*16 + col;
        int cidx = (ks*4 + kg) ^ (tr & 7);
        s16x8 kf = *(const s16x8*)((const char*)Ks[buf] + tr*128 + cidx*16);
        st[f] = mfma16(kf, qk, st[f]);
      }
    }

    // per-lane max of 16 (max3-friendly tree)
    float p0 = fmaxf(fmaxf(st[0][0],st[0][1]), fmaxf(st[0][2],st[0][3]));
    float p1 = fmaxf(fmaxf(st[1][0],st[1][1]), fmaxf(st[1][2],st[1][3]));
    float p2 = fmaxf(fmaxf(st[2][0],st[2][1]), fmaxf(st[2][2],st[2][3]));
    float p3 = fmaxf(fmaxf(st[3][0],st[3][1]), fmaxf(st[3][2],st[3][3]));
    float pm = fmaxf(fmaxf(p0,p1), fmaxf(p2,p3));

    // defer-max: only rescale when max grew past THR (wave-uniform branch)
    if (__any(pm > m + 4.0f)){
      float pm2 = fmaxf(pm, __shfl_xor(pm, 16));
      pm2 = fmaxf(pm2, __shfl_xor(pm2, 32));
      float mn = fmaxf(m, pm2);
      float corr = exp2f(m - mn);
      l *= corr;
      #pragma unroll
      for (int mf=0; mf<4; ++mf) o[mf] *= corr;
      m = mn;
    }

    float ls = 0.f;
    #pragma unroll
    for (int f=0; f<4; ++f)
      #pragma unroll
      for (int r=0; r<4; ++r){
        float p = exp2f(st[f][r] - m);
        st[f][r] = p;
        ls += p;
      }
    l += ls;

    // pack P -> per-wave LDS [q][t] (XOR swizzle, 8B-granule-preserving)
    #pragma unroll
    for (int f=0; f<4; ++f){
      unsigned int lo = pack2(st[f][0], st[f][1]);
      unsigned int hi = pack2(st[f][2], st[f][3]);
      int off = ((f*32 + kg*8) ^ ((col&7)<<4)) >> 1;   // in shorts
      *(uint2*)&Pl[w][col*64 + off] = make_uint2(lo, hi);
    }

    // O^T += V^T * P^T   (rows dv, cols q)
    #pragma unroll
    for (int ks=0; ks<2; ++ks){
      int roff = ((ks*64 + kg*16) ^ ((col&7)<<4)) >> 1; // in shorts
      s16x8 pf = *(const s16x8*)&Pl[w][col*64 + roff];
      #pragma unroll
      for (int mf=0; mf<4; ++mf){
        int dv = mf*16 + col;
        int cidx = (ks*4 + kg) ^ (dv & 7);
        s16x8 vf = *(const s16x8*)((const char*)Vs[buf] + dv*128 + cidx*16);
        o[mf] = mfma16(vf, pf, o[mf]);
      }
    }
    buf ^= 1;
  }

  // final l reduce across kg groups (same q = col)
  l += __shfl_xor(l, 16);
  l += __shfl_xor(l, 32);
  float rcl = 1.0f / l;
  short* og = cc + ((size_t)(b*2048 + qrow))*1024 + h*64;
  #pragma unroll
  for (int mf=0; mf<4; ++mf){
    unsigned int lo = pack2(o[mf][0]*rcl, o[mf][1]*rcl);
    unsigned int hi = pack2(o[mf][2]*rcl, o[mf][3]*rcl);
    *(uint2*)&og[mf*16 + kg*4] = make_uint2(lo, hi);
  }
}

// ---------------- launch ----------------

extern "C" void kernel_launch(void* const* d_in, const int* in_sizes, int n_in,
                              void* d_out, int out_size, void* d_ws, size_t ws_size,
                              hipStream_t stream){
  const float* q  = (const float*)d_in[0];
  const float* k  = (const float*)d_in[1];
  const float* v  = (const float*)d_in[2];
  const float* wq = (const float*)d_in[3];
  const float* wk = (const float*)d_in[4];
  const float* wv = (const float*)d_in[5];
  const float* wo = (const float*)d_in[6];
  const float* bo = (const float*)d_in[7];
  short* ws = (short*)d_ws;
  float* out = (float*)d_out;

  // ws layout (bf16 elems): [0,3SZ) A_q/A_k/A_v (concat reuses [0,SZ) later)
  // [3SZ) qp, [4SZ) kp, [5SZ) vT, [6SZ) BtQ,BtK,BtV, [6SZ+3WSZ) BtO
  size_t needed = (6*SZ + 4*WSZ)*sizeof(short);
  if (ws_size < needed) return;

  convert_misc<<<2048, 256, 0, stream>>>(q, k, v, wo, ws);
  convert_wqkv<<<768, 256, 0, stream>>>(wq, wk, wv, ws);
  gemm_qkv<<<1536, 256, 0, stream>>>(ws);
  attn<<<2048, 256, 0, stream>>>(ws + 3*SZ, ws + 4*SZ, ws + 5*SZ, ws);
  gemm_out<<<512, 256, 0, stream>>>(ws, ws + 6*SZ + 3*WSZ, bo, out);
}